// Round 8
// baseline (265.690 us; speedup 1.0000x reference)
//
#include <hip/hip_runtime.h>
#include <math.h>

#define BB 4
#define NN 128
#define LK 16384      // n*n
#define DD 64
#define HH 4
#define DHH 16
#define QK_SCALE 0.3606737602f   // 0.25 * log2(e): exp(d/4) == exp2(d*QK_SCALE)

__device__ __forceinline__ float fexp2(float x){
#if __has_builtin(__builtin_amdgcn_exp2f)
  return __builtin_amdgcn_exp2f(x);   // v_exp_f32
#else
  return __expf(x * 0.6931471806f);
#endif
}

// ---- mask dtype classification via wave ballots: 0=int32, 1=uint8, 2=float32
__device__ __forceinline__ int compute_mode(const void* __restrict__ qmask){
  const unsigned int* w = (const unsigned int*)qmask;
  const int t = threadIdx.x & 63;
  int u8 = 0, i32 = 0, f32 = 0;
  #pragma unroll
  for (int rep = 0; rep < 2; ++rep){
    const unsigned int x = w[t + rep*64];   // first 512B: in-bounds for every dtype
    const bool one  = (x == 1u);
    const bool fone = (x == 0x3f800000u);
    const bool nz   = (x != 0u);
    u8  += __popcll(__ballot(nz && !one && !fone));
    i32 += __popcll(__ballot(one));
    f32 += __popcll(__ballot(fone));
  }
  int mode = 0;
  if (u8 > i32 && u8 > f32) mode = 1;
  else if (f32 > i32) mode = 2;
  return mode;
}

__device__ __forceinline__ bool mget(const void* __restrict__ p, int idx, int mode){
  if (mode == 1) return ((const unsigned char*)p)[idx] != 0;
  if (mode == 2) return ((const float*)p)[idx] != 0.0f;
  return ((const int*)p)[idx] != 0;
}

__device__ __forceinline__ float dot16(float4 q0, float4 q1, float4 q2, float4 q3,
                                       float4 k0, float4 k1, float4 k2, float4 k3){
  float d;
  d = q0.x*k0.x;         d = fmaf(q0.y,k0.y,d); d = fmaf(q0.z,k0.z,d); d = fmaf(q0.w,k0.w,d);
  d = fmaf(q1.x,k1.x,d); d = fmaf(q1.y,k1.y,d); d = fmaf(q1.z,k1.z,d); d = fmaf(q1.w,k1.w,d);
  d = fmaf(q2.x,k2.x,d); d = fmaf(q2.y,k2.y,d); d = fmaf(q2.z,k2.z,d); d = fmaf(q2.w,k2.w,d);
  d = fmaf(q3.x,k3.x,d); d = fmaf(q3.y,k3.y,d); d = fmaf(q3.z,k3.z,d); d = fmaf(q3.w,k3.w,d);
  return d;
}

// stage ALL 128 q rows into LDS, pre-scaled by QK_SCALE (fully coalesced)
__device__ __forceinline__ void stage_q_all(const float* __restrict__ qA, int b,
                                            float* __restrict__ ldsQ){
  const int t = threadIdx.x;
  const float4* src = (const float4*)(qA + ((size_t)(b*NN))*DD);
  #pragma unroll
  for (int p = 0; p < 8; ++p){
    const int f = p*256 + t;                // float4 index 0..2047 over 32KB
    float4 v = src[f];
    v.x *= QK_SCALE; v.y *= QK_SCALE; v.z *= QK_SCALE; v.w *= QK_SCALE;
    *(float4*)(ldsQ + (f >> 4)*DD + (f & 15)*4) = v;
  }
}

// per-lane k fragment (own l, own head) straight from global: 64B = 4 float4
__device__ __forceinline__ void load_kfrag(const float* __restrict__ kA, int b, int l,
                                           int hs, float4 k[4]){
  const float4* kp = (const float4*)(kA + ((size_t)(b*LK + l))*DD + hs*DHH);
  #pragma unroll
  for (int p = 0; p < 4; ++p) k[p] = kp[p];
}

// ---- pass 1: per-(h,row) sum of exp2 over this block's l-span ----
// Block = (lc, b). wave = head, lane = l. q from 32KB ldsQ broadcast; k in regs.
// 4 rounds of 32 rows (s[32] accumulators), LSUB l-subchunks per block.
template<int LSUB>
__global__ __launch_bounds__(256) void k1_rowsum(
    const float* __restrict__ qA, const float* __restrict__ kA,
    const void* __restrict__ qm, const void* __restrict__ km,
    float* __restrict__ partials)
{
  __shared__ float ldsQ[NN*DD];        // 32 KB
  __shared__ float ldsP[HH][32];
  const int mode = compute_mode(qm);
  const int lc = blockIdx.x, b = blockIdx.y;
  const int t = threadIdx.x, w = t >> 6, ll = t & 63;
  const int hs = __builtin_amdgcn_readfirstlane(w);    // uniform head index

  stage_q_all(qA, b, ldsQ);

  // hoisted lane state for the single-subchunk case
  float4 kf[4];
  int jn0 = 0, kn0 = 0; unsigned kv0 = 0;
  if constexpr (LSUB == 1){
    const int l = lc*64 + ll;
    jn0 = l >> 7; kn0 = l & 127;
    kv0 = ((jn0 != kn0) && mget(km, b*LK + l, mode)) ? 0xFFFFFFFFu : 0u;
    load_kfrag(kA, b, l, hs, kf);
  }
  __syncthreads();

  for (int r = 0; r < 4; ++r){
    const int ibase = r*32;
    float s[32];
    #pragma unroll
    for (int i = 0; i < 32; ++i) s[i] = 0.0f;

    #pragma unroll
    for (int ls = 0; ls < LSUB; ++ls){
      int jn, kn; unsigned kvu;
      if constexpr (LSUB == 1){
        jn = jn0; kn = kn0; kvu = kv0;
      } else {
        const int l = (lc*LSUB + ls)*64 + ll;
        jn = l >> 7; kn = l & 127;
        kvu = ((jn != kn) && mget(km, b*LK + l, mode)) ? 0xFFFFFFFFu : 0u;
        load_kfrag(kA, b, l, hs, kf);
      }
      unsigned vm = kvu;
      if ((unsigned)(jn - ibase) < 32u) vm &= ~(1u << (jn - ibase));
      if ((unsigned)(kn - ibase) < 32u) vm &= ~(1u << (kn - ibase));

      #pragma unroll
      for (int i = 0; i < 32; ++i){
        const float* qp = ldsQ + (ibase + i)*DD + hs*DHH;  // uniform -> broadcast
        float d = dot16(*(const float4*)(qp),   *(const float4*)(qp+4),
                        *(const float4*)(qp+8), *(const float4*)(qp+12),
                        kf[0], kf[1], kf[2], kf[3]);
        d = (vm & (1u << i)) ? d : -INFINITY;              // exp2(-inf)=0
        s[i] += fexp2(d);
      }
    }

    #pragma unroll
    for (int i = 0; i < 32; ++i){
      float v = s[i];
      #pragma unroll
      for (int off = 32; off; off >>= 1) v += __shfl_xor(v, off);
      if (ll == 0) ldsP[w][i] = v;
    }
    __syncthreads();
    if (t < HH*32){                    // t = h*32 + i
      const int h = t >> 5, i = t & 31;
      const bool qv = mget(qm, b*NN + ibase + i, mode);
      partials[(size_t)lc*(BB*HH*NN) + (b*HH + h)*NN + ibase + i] = qv ? ldsP[h][i] : 0.0f;
    }
    __syncthreads();                   // protect ldsP for next round
  }
}

// ---- pass 1b: reduce partials over lc -> reciprocal row sums ----
__global__ void k1_finalize(const float* __restrict__ partials, float* __restrict__ R,
                            int nl){
  const int tid = blockIdx.x*256 + threadIdx.x;   // 0..2047 = (b*HH+h)*NN+ig
  float ssum = 0.0f;
  for (int lc = 0; lc < nl; ++lc) ssum += partials[(size_t)lc*(BB*HH*NN) + tid];
  R[tid] = (ssum > 0.0f) ? 1.0f/ssum : 0.0f;
}

// ---- pass 2: recompute logits, write normalized alpha ----
// Block = (lc, b): k-frag in regs (loaded once), all 128 q-rows from ldsQ,
// R from ldsR. 128-iter straight-line loop, 256B-contiguous wave stores.
__global__ __launch_bounds__(256) void k2_emit(
    const float* __restrict__ qA, const float* __restrict__ kA,
    const void* __restrict__ qm, const void* __restrict__ km,
    const float* __restrict__ R, float* __restrict__ out)
{
  __shared__ float ldsQ[NN*DD];        // 32 KB
  __shared__ float ldsR[HH*NN];        // 2 KB
  const int mode = compute_mode(qm);
  const int lc = blockIdx.x, b = blockIdx.y;
  const int t = threadIdx.x, w = t >> 6, ll = t & 63;
  const int hs = __builtin_amdgcn_readfirstlane(w);
  const int l  = lc*64 + ll;

  stage_q_all(qA, b, ldsQ);
  for (int f = t; f < HH*NN; f += 256) ldsR[f] = R[b*HH*NN + f];

  float4 kf[4];
  load_kfrag(kA, b, l, hs, kf);

  const int jn = l >> 7, kn = l & 127;
  const bool kv = (jn != kn) && mget(km, b*LK + l, mode);
  // q-mask omitted on purpose: masked q-rows have R==0 (K1 zeroes them)
  unsigned long long m0 = kv ? ~0ull : 0ull, m1 = m0;
  if (jn < 64) m0 &= ~(1ull << jn); else m1 &= ~(1ull << (jn - 64));
  if (kn < 64) m0 &= ~(1ull << kn); else m1 &= ~(1ull << (kn - 64));
  __syncthreads();

  const float* Rh = ldsR + hs*NN;
  float* op = out + (((size_t)((hs*BB + b)*NN)) << 14) + lc*64 + ll;

  #pragma unroll 8
  for (int i = 0; i < NN; ++i){
    const float* qp = ldsQ + i*DD + hs*DHH;        // uniform -> LDS broadcast
    float d = dot16(*(const float4*)(qp),   *(const float4*)(qp+4),
                    *(const float4*)(qp+8), *(const float4*)(qp+12),
                    kf[0], kf[1], kf[2], kf[3]);
    const unsigned long long mm = (i & 64) ? m1 : m0;
    d = ((mm >> (i & 63)) & 1ull) ? d : -INFINITY;
    op[((size_t)i) << 14] = fexp2(d) * Rh[i];      // 64 lanes -> 256B contiguous
  }
}

extern "C" void kernel_launch(void* const* d_in, const int* in_sizes, int n_in,
                              void* d_out, int out_size, void* d_ws, size_t ws_size,
                              hipStream_t stream)
{
  const float* qA = (const float*)d_in[0];
  const float* kA = (const float*)d_in[1];
  const void*  qm = d_in[2];
  const void*  km = d_in[3];
  float* out = (float*)d_out;

  const size_t PB = (size_t)BB*HH*NN;              // 2048 rows
  float* partials = (float*)d_ws;

  // pick l-split by available workspace: NLc blocks per b, LSUB subchunks each
  int NLc, LS;
  if      (ws_size >= (256*PB + PB)*sizeof(float)) { NLc = 256; LS = 1; }
  else if (ws_size >= (128*PB + PB)*sizeof(float)) { NLc = 128; LS = 2; }
  else                                             { NLc = 64;  LS = 4; }
  float* R = partials + (size_t)NLc*PB;

  dim3 g1(NLc, BB);
  if      (LS == 1) k1_rowsum<1><<<g1, 256, 0, stream>>>(qA, kA, qm, km, partials);
  else if (LS == 2) k1_rowsum<2><<<g1, 256, 0, stream>>>(qA, kA, qm, km, partials);
  else              k1_rowsum<4><<<g1, 256, 0, stream>>>(qA, kA, qm, km, partials);
  k1_finalize<<<(int)(PB/256), 256, 0, stream>>>(partials, R, NLc);
  dim3 g2(LK/64, BB);                 // (256, 4) = 1024 blocks, 4/CU full residency
  k2_emit<<<g2, 256, 0, stream>>>(qA, kA, qm, km, R, out);
}

// Round 9
// 69.281 us; speedup vs baseline: 3.8350x; 3.8350x over previous
//
#include <hip/hip_runtime.h>
#include <math.h>

#define BB 4
#define NN 128
#define LK 16384      // n*n
#define DD 64
#define HH 4
#define DHH 16
#define TI2 32        // q-rows per block
#define KROWS 64      // K1 staged k rows per chunk
#define KPAD 68       // floats per LDS row (272B)
#define L1CH 256      // K1 l-span per block (4 chunks of 64)
#define NL1 (LK/L1CH) // 64
#define QK_SCALE 0.3606737602f   // 0.25 * log2(e): exp(d/4) == exp2(d*QK_SCALE)

__device__ __forceinline__ float fexp2(float x){
#if __has_builtin(__builtin_amdgcn_exp2f)
  return __builtin_amdgcn_exp2f(x);   // v_exp_f32
#else
  return __expf(x * 0.6931471806f);
#endif
}

// ---- mask dtype classification via wave ballots: 0=int32, 1=uint8, 2=float32
__device__ __forceinline__ int compute_mode(const void* __restrict__ qmask){
  const unsigned int* w = (const unsigned int*)qmask;
  const int t = threadIdx.x & 63;
  int u8 = 0, i32 = 0, f32 = 0;
  #pragma unroll
  for (int rep = 0; rep < 2; ++rep){
    const unsigned int x = w[t + rep*64];   // first 512B: in-bounds for every dtype
    const bool one  = (x == 1u);
    const bool fone = (x == 0x3f800000u);
    const bool nz   = (x != 0u);
    u8  += __popcll(__ballot(nz && !one && !fone));
    i32 += __popcll(__ballot(one));
    f32 += __popcll(__ballot(fone));
  }
  int mode = 0;
  if (u8 > i32 && u8 > f32) mode = 1;
  else if (f32 > i32) mode = 2;
  return mode;
}

__device__ __forceinline__ bool mget(const void* __restrict__ p, int idx, int mode){
  if (mode == 1) return ((const unsigned char*)p)[idx] != 0;
  if (mode == 2) return ((const float*)p)[idx] != 0.0f;
  return ((const int*)p)[idx] != 0;
}

__device__ __forceinline__ float dot16(float4 q0, float4 q1, float4 q2, float4 q3,
                                       float4 k0, float4 k1, float4 k2, float4 k3){
  float d;
  d = q0.x*k0.x;         d = fmaf(q0.y,k0.y,d); d = fmaf(q0.z,k0.z,d); d = fmaf(q0.w,k0.w,d);
  d = fmaf(q1.x,k1.x,d); d = fmaf(q1.y,k1.y,d); d = fmaf(q1.z,k1.z,d); d = fmaf(q1.w,k1.w,d);
  d = fmaf(q2.x,k2.x,d); d = fmaf(q2.y,k2.y,d); d = fmaf(q2.z,k2.z,d); d = fmaf(q2.w,k2.w,d);
  d = fmaf(q3.x,k3.x,d); d = fmaf(q3.y,k3.y,d); d = fmaf(q3.z,k3.z,d); d = fmaf(q3.w,k3.w,d);
  return d;
}

// stage KROWS k-records (256B each) into padded LDS; fully coalesced (K1 only)
__device__ __forceinline__ void stage_k(const float* __restrict__ kA, int b, int lbase,
                                        float* __restrict__ ldsK){
  const int t = threadIdx.x;
  const float4* src = (const float4*)(kA + ((size_t)(b*LK + lbase))*DD);
  #pragma unroll
  for (int p = 0; p < 4; ++p){
    const int f = p*256 + t;          // float4 index 0..1023 over 16KB
    const float4 v = src[f];
    *(float4*)(ldsK + (f >> 4)*KPAD + (f & 15)*4) = v;
  }
}

// stage TI2 q-rows, pre-scaled by QK_SCALE
__device__ __forceinline__ void stage_q(const float* __restrict__ qA, int b, int ibase,
                                        float* __restrict__ ldsQ){
  const int t = threadIdx.x;
  const float4* src = (const float4*)(qA + ((size_t)(b*NN + ibase))*DD);
  #pragma unroll
  for (int p = 0; p < 2; ++p){
    const int f = p*256 + t;          // 0..511 over 8KB
    float4 v = src[f];
    v.x *= QK_SCALE; v.y *= QK_SCALE; v.z *= QK_SCALE; v.w *= QK_SCALE;
    *(float4*)(ldsQ + (f >> 4)*DD + (f & 15)*4) = v;
  }
}

// ---- pass 1: per-(h,row) sum of exp2 over this block's 256-l span ----
// (byte-faithful R3 k1 + exp2 fold)
__global__ __launch_bounds__(256) void k1_rowsum(
    const float* __restrict__ qA, const float* __restrict__ kA,
    const void* __restrict__ qm, const void* __restrict__ km,
    float* __restrict__ partials)
{
  __shared__ float ldsK[KROWS*KPAD];
  __shared__ float ldsQ[TI2*DD];
  __shared__ float ldsP[HH][TI2];
  const int mode = compute_mode(qm);
  const int lc = blockIdx.x, it = blockIdx.y, b = blockIdx.z;
  const int t = threadIdx.x, w = t >> 6, ll = t & 63;
  const int ibase = it*TI2;

  stage_q(qA, b, ibase, ldsQ);

  float s[TI2];
  #pragma unroll
  for (int i = 0; i < TI2; ++i) s[i] = 0.0f;

  for (int jj = 0; jj < L1CH/KROWS; ++jj){
    if (jj) __syncthreads();                 // prior chunk's readers done
    stage_k(kA, b, lc*L1CH + jj*KROWS, ldsK);
    __syncthreads();

    const int l  = lc*L1CH + jj*KROWS + ll;
    const int jn = l >> 7, kn = l & 127;
    const bool kv = (jn != kn) && mget(km, (b << 14) + l, mode);
    unsigned vmask = kv ? 0xFFFFFFFFu : 0u;
    if ((unsigned)(jn - ibase) < TI2) vmask &= ~(1u << (jn - ibase));
    if ((unsigned)(kn - ibase) < TI2) vmask &= ~(1u << (kn - ibase));

    const float* kp = ldsK + ll*KPAD + w*DHH;   // wave w owns head h=w
    const float4 k0 = *(const float4*)(kp),    k1 = *(const float4*)(kp+4),
                 k2 = *(const float4*)(kp+8),  k3 = *(const float4*)(kp+12);

    #pragma unroll
    for (int i = 0; i < TI2; ++i){              // full unroll: s[i] stays in regs
      const float* qp = ldsQ + i*DD + w*DHH;    // wave-uniform -> broadcast
      float d = dot16(*(const float4*)(qp),   *(const float4*)(qp+4),
                      *(const float4*)(qp+8), *(const float4*)(qp+12),
                      k0, k1, k2, k3);
      d = (vmask & (1u << i)) ? d : -INFINITY;  // exp2(-inf)=0
      s[i] += fexp2(d);
    }
  }

  #pragma unroll
  for (int i = 0; i < TI2; ++i){
    float v = s[i];
    #pragma unroll
    for (int off = 32; off; off >>= 1) v += __shfl_xor(v, off);
    if (ll == 0) ldsP[w][i] = v;
  }
  __syncthreads();
  if (t < HH*TI2){                 // t = h*32 + i
    const int h = t >> 5, i = t & 31;
    const bool qv = mget(qm, b*NN + ibase + i, mode);
    partials[((lc*BB + b)*HH + h)*NN + ibase + i] = qv ? ldsP[h][i] : 0.0f;
  }
}

// ---- pass 1b: reduce partials over lc -> reciprocal row sums ----
__global__ void k1_finalize(const float* __restrict__ partials, float* __restrict__ R){
  const int tid = blockIdx.x*256 + threadIdx.x;   // 0..2047 = (b*HH+h)*NN+ig
  float ssum = 0.0f;
  for (int lc = 0; lc < NL1; ++lc) ssum += partials[lc*(BB*HH*NN) + tid];
  R[tid] = (ssum > 0.0f) ? 1.0f/ssum : 0.0f;
}

// ---- pass 2: lane owns 4 consecutive l (k in 64 VGPRs); q+R from small LDS;
// float4 stores (1KB/wave contiguous). LDS total ~8.5KB -> occupancy VGPR-bound.
__global__ __launch_bounds__(256) void k2_emit(
    const float* __restrict__ qA, const float* __restrict__ kA,
    const void* __restrict__ qm, const void* __restrict__ km,
    const float* __restrict__ R, float* __restrict__ out)
{
  __shared__ float ldsQ[TI2*DD];       // 8 KB
  __shared__ float ldsR[HH*TI2];       // 512 B
  const int mode = compute_mode(qm);
  const int lc = blockIdx.x, it = blockIdx.y, b = blockIdx.z;
  const int t = threadIdx.x, w = t >> 6, ll = t & 63;
  const int ibase = it*TI2;
  const int lbase = lc*256 + ll*4;     // this lane's first l

  stage_q(qA, b, ibase, ldsQ);
  if (t < HH*TI2){                     // t = h*32 + i
    ldsR[t] = R[(b*HH + (t >> 5))*NN + ibase + (t & 31)];
  }

  // k for 4 consecutive rows (own head) straight from global (one-time, L2-hot)
  float4 kk[4][4];
  #pragma unroll
  for (int e = 0; e < 4; ++e){
    const float4* kp = (const float4*)(kA + ((size_t)(b*LK + lbase + e))*DD + w*DHH);
    #pragma unroll
    for (int p = 0; p < 4; ++p) kk[e][p] = kp[p];
  }

  unsigned vm[4];
  #pragma unroll
  for (int e = 0; e < 4; ++e){
    const int l = lbase + e;
    const int jn = l >> 7, kn = l & 127;
    const bool kv = (jn != kn) && mget(km, b*LK + l, mode);
    unsigned m = kv ? 0xFFFFFFFFu : 0u;
    if ((unsigned)(jn - ibase) < TI2) m &= ~(1u << (jn - ibase));
    if ((unsigned)(kn - ibase) < TI2) m &= ~(1u << (kn - ibase));
    vm[e] = m;   // q-mask not needed: masked q-rows have R==0
  }
  __syncthreads();

  float* op = out + (((size_t)((w*BB + b)*NN + ibase)) << 14) + lbase;

  #pragma unroll 2
  for (int i = 0; i < TI2; ++i){
    const float* qp = ldsQ + i*DD + w*DHH;     // wave-uniform -> LDS broadcast
    const float4 q0 = *(const float4*)(qp),   q1 = *(const float4*)(qp+4),
                 q2 = *(const float4*)(qp+8), q3 = *(const float4*)(qp+12);
    const float r = ldsR[w*TI2 + i];           // wave-uniform LDS read
    float4 o;
    o.x = fexp2((vm[0] & (1u<<i)) ? dot16(q0,q1,q2,q3, kk[0][0],kk[0][1],kk[0][2],kk[0][3]) : -INFINITY) * r;
    o.y = fexp2((vm[1] & (1u<<i)) ? dot16(q0,q1,q2,q3, kk[1][0],kk[1][1],kk[1][2],kk[1][3]) : -INFINITY) * r;
    o.z = fexp2((vm[2] & (1u<<i)) ? dot16(q0,q1,q2,q3, kk[2][0],kk[2][1],kk[2][2],kk[2][3]) : -INFINITY) * r;
    o.w = fexp2((vm[3] & (1u<<i)) ? dot16(q0,q1,q2,q3, kk[3][0],kk[3][1],kk[3][2],kk[3][3]) : -INFINITY) * r;
    *(float4*)(op + (((size_t)i) << 14)) = o;  // 64 lanes -> 1KB contiguous
  }
}

extern "C" void kernel_launch(void* const* d_in, const int* in_sizes, int n_in,
                              void* d_out, int out_size, void* d_ws, size_t ws_size,
                              hipStream_t stream)
{
  const float* qA = (const float*)d_in[0];
  const float* kA = (const float*)d_in[1];
  const void*  qm = d_in[2];
  const void*  km = d_in[3];
  float* out = (float*)d_out;

  float* partials = (float*)d_ws;                    // NL1*2048 floats = 512KB
  float* R        = partials + (size_t)NL1*BB*HH*NN;

  dim3 g1(NL1, NN/TI2, BB);        // (64, 4, 4) = 1024 blocks
  k1_rowsum<<<g1, 256, 0, stream>>>(qA, kA, qm, km, partials);
  k1_finalize<<<(BB*HH*NN)/256, 256, 0, stream>>>(partials, R);
  dim3 g2(LK/256, NN/TI2, BB);     // (64, 4, 4) = 1024 blocks
  k2_emit<<<g2, 256, 0, stream>>>(qA, kA, qm, km, R, out);
}